// Round 19
// baseline (188.113 us; speedup 1.0000x reference)
//
#include <hip/hip_runtime.h>
#include <hip/hip_bf16.h>
#include <math.h>

#define T_LEN   320000
#define NB      16
#define NROWS   32          // 16 batch * 2 ch
#define NFRAMES 625
#define NCOMP   67
#define NCH     150
#define HOPSZ   512
#define BREP    8           // B-table replicas
#define BSZ     491520      // ushorts per B copy

typedef __attribute__((ext_vector_type(8))) _Float16 half8v;
typedef __attribute__((ext_vector_type(8))) short short8v;
typedef __attribute__((ext_vector_type(4))) float f32x4;

// per-window constants
__constant__ int cW_N[6]  = {2048,1024,512,256,128,64};
__constant__ int cW_K0[6] = {2,3,8,10,11,9};
__constant__ int cW_CB[7] = {0,4,17,29,40,46,67};
__constant__ int cW_CO[7] = {0,8192,21504,27648,30464,31232,32576};
// fused-coefficient geometry (per window)
__constant__ int dNEp[6]  = {3072,2048,1536,1280,1152,1152};
__constant__ int dNEr[6]  = {3072,2048,1536,1280,1152,1088};
__constant__ int dBTb[7]  = {0,147456,245760,319488,380928,436224,491520}; // [w][col=48][k=NEp] ushort
// init_fused chunk mapping
__constant__ int dCPB[6]  = {12,8,6,5,5,5};
__constant__ int dCKB[7]  = {0,48,152,224,279,309,414};
// edge task list
__constant__ int eW[8] = {0,0,0,1,2,3,4,5};
__constant__ int eF[8] = {0,1,624,0,0,0,0,0};

// ---- uniform gemm task table: 12 tasks over 8 waves (fp16, 1-term) ----
__constant__ int tBb[12]   = {147456,180224,0,380928,0,436224,245760,454656,270336,473088,319488,339968};
__constant__ int tNEp[12]  = {2048,2048,3072,1152,3072,1152,1536,1152,1536,1152,1280,1280};
__constant__ int tStb[12]  = {512,512,0,960,0,992,768,992,768,992,896,896};
__constant__ int tKs0[12]  = {0,0,0,0,48,0,0,0,0,0,0,0};
__constant__ int tKs1[12]  = {64,64,48,36,96,36,48,36,48,36,40,40};
__constant__ int tJadd[12] = {4,12,0,40,0,46,17,54,25,62,29,37};
__constant__ int tNbL[12]  = {13,5,4,6,4,21,12,13,4,5,11,3};
__constant__ int tMode[12] = {0,0,1,0,2,0,0,0,0,0,0,0};
__constant__ int wStart[8] = {0,1,2,4,6,8,10,11};
__constant__ int wCnt[8]   = {1,1,2,2,2,2,1,1};

__device__ __forceinline__ unsigned short f2bf(float v) {
  unsigned u = __float_as_uint(v);
  return (unsigned short)((u + 0x7FFFu + ((u >> 16) & 1u)) >> 16);
}

// ================= setup: tables + fused fp16 B (x8) + edge FIR + roex-bf16 =================
// blocks [0,167): init_tables ; [167,581): init_fused ; [581,965): edge_y ; 965: Wb16
__global__ __launch_bounds__(256) void setup_k(const float* __restrict__ h,
                                               const float* __restrict__ x,
                                               float2* __restrict__ coeff,
                                               float* __restrict__ Wmat,
                                               float* __restrict__ gauss,
                                               unsigned short* __restrict__ Bf,
                                               float* __restrict__ ye,
                                               unsigned short* __restrict__ Wb16) {
  __shared__ __align__(16) float sm[3585];
  const int bid = blockIdx.x, tid = threadIdx.x;
  if (bid < 167) {
    int gid = bid * 256 + tid;
    if (gid < 32576) {
      int w = 0;
      while (gid >= cW_CO[w + 1]) ++w;
      int local = gid - cW_CO[w];
      int N = cW_N[w];
      int jloc = local / N;
      int n = local - jloc * N;
      int k = cW_K0[w] + jloc;
      float win = 0.5f - 0.5f * cospif(2.0f * (float)n / (float)(N - 1));
      int r = (int)(((long long)k * (long long)n) % (long long)N);
      float ang = 2.0f * (float)r / (float)N;
      float scale = sqrtf(2.0f) / (0.5f * (float)(N - 1));
      float wc = win * scale;
      coeff[gid] = make_float2(wc * cospif(ang), wc * sinpif(ang));
    } else if (gid < 32576 + NCOMP * NCH) {
      int t = gid - 32576;
      int j = t / NCH, c = t - j * NCH;
      float erb = 1.75f + 0.25f * (float)c;
      float fc = (exp10f(erb * (1.0f / 21.366f)) - 1.0f) * (1.0f / 0.004368f);
      float erbw = 24.673f * (0.004368f * fc + 1.0f);
      float p = 4.0f * fc / erbw;
      int w = 0;
      while (j >= cW_CB[w + 1]) ++w;
      float freq = (float)(cW_K0[w] + (j - cW_CB[w])) * (32000.0f / (float)cW_N[w]);
      float g = fabsf(freq / fc - 1.0f);
      float pg = p * g;
      Wmat[j * NCH + c] = (1.0f + pg) * expf(-pg);
    } else if (gid == 32576 + NCOMP * NCH) {
      float tmp[17]; float s = 0.0f;
      for (int k = 0; k < 17; ++k) {
        float g = ((float)k - 8.0f) * 0.25f;
        tmp[k] = expf(-g * g / (2.0f * 0.08f * 0.08f));
        s += tmp[k];
      }
      for (int k = 0; k < 17; ++k) gauss[k] = tmp[k] / s;
    }
  } else if (bid < 581) {
    float* cre_l = sm;          // 1280
    float* cim_l = sm + 1280;   // 1280
    float* hs    = sm + 2560;   // 1025
    const int b2 = bid - 167;
    int w = 0;
    while (b2 >= dCKB[w + 1]) ++w;
    const int local = b2 - dCKB[w];
    const int jloc = local / dCPB[w];
    const int chunk = local - jloc * dCPB[w];
    const int N = cW_N[w];
    const int k = cW_K0[w] + jloc;
    const int NEp = dNEp[w], NEr = dNEr[w];
    const int v0 = chunk * 256;
    const int nlo_blk = max(0, v0 - 1024);
    const int nhi_blk = min(N - 1, v0 + 255);
    const int cnt_n = nhi_blk - nlo_blk + 1;
    const float scale = sqrtf(2.0f) / (0.5f * (float)(N - 1));
    for (int i = tid; i < 1025; i += 256) hs[i] = h[i];
    for (int i = tid; i < cnt_n; i += 256) {
      int n = nlo_blk + i;
      float win = 0.5f - 0.5f * cospif(2.0f * (float)n / (float)(N - 1));
      int r = (int)(((long long)k * (long long)n) % (long long)N);
      float ang = 2.0f * (float)r / (float)N;
      float wc = win * scale;
      cre_l[i] = wc * cospif(ang);
      cim_l[i] = wc * sinpif(ang);
    }
    __syncthreads();
    const int v = v0 + tid;
    if (v >= NEp) return;
    float re = 0.0f, im = 0.0f;
    if (v < NEr) {
      const int n0 = max(nlo_blk, v - 1024);
      const int n1 = min(nhi_blk, v);
      float r0 = 0.f, r1 = 0.f, r2 = 0.f, r3 = 0.f;
      float m0 = 0.f, m1 = 0.f, m2 = 0.f, m3 = 0.f;
      int n = n0;
      const int hoff = 1024 - v, coff = -nlo_blk;
      for (; n + 3 <= n1; n += 4) {
        float h0 = hs[n + hoff],     h1 = hs[n + 1 + hoff];
        float h2 = hs[n + 2 + hoff], h3 = hs[n + 3 + hoff];
        r0 = fmaf(cre_l[n + coff],     h0, r0); m0 = fmaf(cim_l[n + coff],     h0, m0);
        r1 = fmaf(cre_l[n + 1 + coff], h1, r1); m1 = fmaf(cim_l[n + 1 + coff], h1, m1);
        r2 = fmaf(cre_l[n + 2 + coff], h2, r2); m2 = fmaf(cim_l[n + 2 + coff], h2, m2);
        r3 = fmaf(cre_l[n + 3 + coff], h3, r3); m3 = fmaf(cim_l[n + 3 + coff], h3, m3);
      }
      for (; n <= n1; ++n) {
        float hv = hs[n + hoff];
        r0 = fmaf(cre_l[n + coff], hv, r0);
        m0 = fmaf(cim_l[n + coff], hv, m0);
      }
      re = (r0 + r1) + (r2 + r3);
      im = (m0 + m1) + (m2 + m3);
    }
    size_t o0 = (size_t)dBTb[w] + (size_t)(2 * jloc) * NEp + v;
    size_t o1 = o0 + NEp;
    _Float16 hr = (_Float16)re;
    _Float16 hi2 = (_Float16)im;
    unsigned short hrb = *(unsigned short*)&hr;
    unsigned short hib = *(unsigned short*)&hi2;
#pragma unroll
    for (int cp = 0; cp < BREP; ++cp) {
      Bf[(size_t)cp * BSZ + o0] = hrb;
      Bf[(size_t)cp * BSZ + o1] = hib;
    }
  } else if (bid < 965) {
    float* xl = sm;             // 1280  (16B aligned)
    float* hs = sm + 1280;      // 1025  (offset 5120B, 16B aligned)
    const int b2 = bid - 581;
    const int chunk = b2 % 12, row = b2 / 12;
    const size_t rowoff = (size_t)row * T_LEN;
    const int i0 = chunk * 256;
    const int pos0 = (i0 < 1536) ? i0 : 318464 + (i0 - 1536);
    for (int i = tid; i < 1025; i += 256) hs[i] = h[i];
    for (int i = tid; i < 1280; i += 256) {
      int g = pos0 - 512 + i;
      xl[i] = ((unsigned)g < (unsigned)T_LEN) ? x[rowoff + g] : 0.0f;
    }
    __syncthreads();
    float a0 = 0.0f, a1 = 0.0f, a2 = 0.0f, a3 = 0.0f;
    const int d = tid + 1024;
    const float4* hs4 = (const float4*)hs;
    for (int m = 0; m < 1024; m += 4) {
      float4 hv = hs4[m >> 2];          // broadcast ds_read_b128: 4 taps/instr
      a0 = fmaf(hv.x, xl[d - m],     a0);
      a1 = fmaf(hv.y, xl[d - m - 1], a1);
      a2 = fmaf(hv.z, xl[d - m - 2], a2);
      a3 = fmaf(hv.w, xl[d - m - 3], a3);
    }
    float acc = ((a0 + a1) + (a2 + a3)) + hs[1024] * xl[d - 1024];
    ye[(size_t)row * 3072 + i0 + tid] = acc;
  } else {
    // roex table as bf16, B-layout [col=160][k=96]
    for (int u = tid; u < 160 * 96; u += 256) {
      int c = u / 96, j = u - (u / 96) * 96;
      float val = 0.0f;
      if (c < NCH && j < NCOMP) {
        float erb = 1.75f + 0.25f * (float)c;
        float fc = (exp10f(erb * (1.0f / 21.366f)) - 1.0f) * (1.0f / 0.004368f);
        float erbw = 24.673f * (0.004368f * fc + 1.0f);
        float p = 4.0f * fc / erbw;
        int w = 0;
        while (j >= cW_CB[w + 1]) ++w;
        float freq = (float)(cW_K0[w] + (j - cW_CB[w])) * (32000.0f / (float)cW_N[w]);
        float g = fabsf(freq / fc - 1.0f);
        float pg = p * g;
        val = (1.0f + pg) * expf(-pg);
      }
      Wb16[u] = f2bf(val);
    }
  }
}

// ================= MFMA fused FIR+DFT: fp16 single-term, nontemporal streaming =================
#define TILE_X 18944   // 31*512 + 3072
#define SWZ4(i) ((i) ^ ((((i) >> 9) & 15) << 3))

// blocks [0,640): MFMA gemm (fblk = b%20, row = b/20) ; [640,672): edge DFT (row = b-640)
__global__ __launch_bounds__(512) void sparse2(const float* __restrict__ x,
                                               const unsigned short* __restrict__ Bf,
                                               const float2* __restrict__ coeff,
                                               const float* __restrict__ ye,
                                               float* __restrict__ Ibuf) {
  __shared__ __align__(16) unsigned short sxh[TILE_X];   // fp16 x-tile
  __shared__ float redA[512];                            // W0a partials (2 KB)
  const int b = blockIdx.x, tid = threadIdx.x;
  if (b < 640) {
    const int fblk = b % 20, row = b / 20;
    const int f0 = fblk * 32;
    const float* xr = x + (size_t)row * T_LEN;
    const unsigned short* Bc = Bf + (size_t)(b & (BREP - 1)) * BSZ;
    const int lo = f0 * HOPSZ - 1536;
    for (int i = 4 * tid; i < TILE_X; i += 2048) {
      const int g = lo + i;
      float v[4];
      if (g >= 0 && g + 4 <= T_LEN) {
        f32x4 p = __builtin_nontemporal_load((const f32x4*)(xr + g));   // stream: don't thrash L2
        v[0] = p[0]; v[1] = p[1]; v[2] = p[2]; v[3] = p[3];
      } else {
#pragma unroll
        for (int q = 0; q < 4; ++q) {
          int gg = g + q;
          v[q] = ((unsigned)gg < (unsigned)T_LEN) ? __builtin_nontemporal_load(xr + gg) : 0.0f;
        }
      }
      unsigned short h4[4];
#pragma unroll
      for (int q = 0; q < 4; ++q) {
        _Float16 hv = (_Float16)v[q];
        h4[q] = *(unsigned short*)&hv;
      }
      const int is = SWZ4(i);
      *(ushort4*)(sxh + is) = make_ushort4(h4[0], h4[1], h4[2], h4[3]);
    }
    __syncthreads();
    const int wv = tid >> 6, lane = tid & 63;
    const int fidx = lane & 15, kg = lane >> 4;
    const int t0 = wStart[wv], tcnt = wCnt[wv];
    f32x4 pA = (f32x4){0.f,0.f,0.f,0.f};   // W0b partial (mode 2)
    f32x4 pB = (f32x4){0.f,0.f,0.f,0.f};
    for (int ti = t0; ti < t0 + tcnt; ++ti) {
      const int NEp = tNEp[ti];
      const int ks0 = tKs0[ti], ks1 = tKs1[ti];
      const unsigned short* Bp = Bc + tBb[ti] + fidx * NEp + kg * 8;
      const int ibase = fidx * 512 + tStb[ti] + kg * 8;
      f32x4 acc0 = (f32x4){0.f,0.f,0.f,0.f};
      f32x4 acc1 = (f32x4){0.f,0.f,0.f,0.f};
#pragma unroll 2
      for (int kk = ks0; kk < ks1; ++kk) {
        const int ko = kk * 32;
        half8v bv = *(const half8v*)(Bp + ko);
        half8v a0 = *(const half8v*)(sxh + SWZ4(ibase + ko));
        half8v a1 = *(const half8v*)(sxh + SWZ4(ibase + 8192 + ko));
        acc0 = __builtin_amdgcn_mfma_f32_16x16x32_f16(a0, bv, acc0, 0, 0, 0);
        acc1 = __builtin_amdgcn_mfma_f32_16x16x32_f16(a1, bv, acc1, 0, 0, 0);
      }
      const int mode = tMode[ti];
      if (mode == 0) {
        const int jadd = tJadd[ti], nbl = tNbL[ti];
        const int fh = fidx >> 1;
        const bool jvalid = !(fidx & 1) && fh < nbl;
#pragma unroll
        for (int r = 0; r < 4; ++r) {
          float v0 = acc0[r];
          float sq0 = v0 * v0;
          sq0 += __shfl_xor(sq0, 1);
          int fA = f0 + kg * 4 + r;
          if (jvalid && fA != 0)
            __builtin_nontemporal_store(sq0, &Ibuf[((size_t)row * NFRAMES + fA) * NCOMP + jadd + fh]);
          float v1 = acc1[r];
          float sq1 = v1 * v1;
          sq1 += __shfl_xor(sq1, 1);
          int fB = f0 + 16 + kg * 4 + r;
          if (jvalid && fB < NFRAMES)
            __builtin_nontemporal_store(sq1, &Ibuf[((size_t)row * NFRAMES + fB) * NCOMP + jadd + fh]);
        }
      } else if (mode == 1) {
#pragma unroll
        for (int r = 0; r < 4; ++r) {
          redA[lane * 4 + r] = acc0[r];
          redA[256 + lane * 4 + r] = acc1[r];
        }
      } else {
        pA = acc0; pB = acc1;
      }
    }
    __syncthreads();
    if (wv == 3) {
      // finalize W0: sum K-halves, square, pair re/im, store (jb0=0, nb=4)
#pragma unroll
      for (int r = 0; r < 4; ++r) {
        float v0 = pA[r] + redA[lane * 4 + r];
        float sq0 = v0 * v0;
        sq0 += __shfl_xor(sq0, 1);
        int fA = f0 + kg * 4 + r;
        float v1 = pB[r] + redA[256 + lane * 4 + r];
        float sq1 = v1 * v1;
        sq1 += __shfl_xor(sq1, 1);
        int fB = f0 + 16 + kg * 4 + r;
        if (!(fidx & 1)) {
          int j = fidx >> 1;
          if (j < 4) {
            bool eA = (fA == 0) || (fA == 1) || (fA == 624);
            if (!eA) __builtin_nontemporal_store(sq0, &Ibuf[((size_t)row * NFRAMES + fA) * NCOMP + j]);
            bool eB = (fB == 1) || (fB == 624);
            if (fB < NFRAMES && !eB) __builtin_nontemporal_store(sq1, &Ibuf[((size_t)row * NFRAMES + fB) * NCOMP + j]);
          }
        }
      }
    }
  } else {
    const int row = b - 640;
    float* yl = (float*)sxh;   // 12 KB alias
    for (int i = tid; i < 3072; i += 512) yl[i] = ye[(size_t)row * 3072 + i];
    __syncthreads();
    const int wv = tid >> 6, lane = tid & 63;
    const int w = eW[wv], f = eF[wv];
    const int N = cW_N[w];
    const int nb = cW_CB[w + 1] - cW_CB[w];
    for (int jl = 0; jl < nb; ++jl) {
      const float2* cf = coeff + cW_CO[w] + (size_t)jl * N;
      float re = 0.0f, im = 0.0f;
      for (int n = lane; n < N; n += 64) {
        int pos = f * HOPSZ - (N >> 1) + n;
        if ((unsigned)pos < (unsigned)T_LEN) {
          int yi = (pos < 1536) ? pos : (pos - 318464 + 1536);
          float yv = yl[yi];
          float2 cs = cf[n];
          re = fmaf(yv, cs.x, re);
          im = fmaf(yv, cs.y, im);
        }
      }
#pragma unroll
      for (int off = 32; off > 0; off >>= 1) {
        re += __shfl_xor(re, off);
        im += __shfl_xor(im, off);
      }
      if (lane == 0)
        Ibuf[((size_t)row * NFRAMES + f) * NCOMP + (cW_CB[w] + jl)] = re * re + im * im;
    }
  }
}

// ================= E = I@W via bf16 MFMA -> dB -> LUT -> n_inst, 64 frames/block =================
__global__ __launch_bounds__(256) void espec(const float* __restrict__ Ibuf,
                                             const unsigned short* __restrict__ Wb16,
                                             const float* __restrict__ lut,
                                             float* __restrict__ ninst) {
  __shared__ __align__(16) unsigned short sxA[64 * 104];   // bf16 I, stride 104
  __shared__ float luts[88];
  const int row = blockIdx.y;
  const int fB = blockIdx.x * 64;
  const int tid = threadIdx.x;
  if (tid < 88) luts[tid] = lut[tid];
  for (int u = tid; u < 64 * 52; u += 256) ((unsigned*)sxA)[u] = 0;
  __syncthreads();
  for (int u = tid; u < 64 * NCOMP; u += 256) {
    int fl = u / NCOMP, j = u - fl * NCOMP;
    int f = fB + fl;
    float v = (f < NFRAMES) ? __builtin_nontemporal_load(&Ibuf[((size_t)row * NFRAMES + f) * NCOMP + j]) : 0.0f;
    sxA[fl * 104 + j] = f2bf(v);
  }
  __syncthreads();
  const int wv = tid >> 6, lane = tid & 63;
  const int fidx = lane & 15, kg = lane >> 4;
  const unsigned short* Ap = sxA + (wv * 16 + fidx) * 104 + kg * 8;
  short8v a0 = *(const short8v*)(Ap);
  short8v a1 = *(const short8v*)(Ap + 32);
  short8v a2 = *(const short8v*)(Ap + 64);
  f32x4 acc[10];
#pragma unroll
  for (int ct = 0; ct < 10; ++ct) acc[ct] = (f32x4){0.f,0.f,0.f,0.f};
#pragma unroll
  for (int ct = 0; ct < 10; ++ct) {
    const unsigned short* Bp = Wb16 + (ct * 16 + fidx) * 96 + kg * 8;
    short8v b0 = *(const short8v*)(Bp);
    short8v b1 = *(const short8v*)(Bp + 32);
    short8v b2 = *(const short8v*)(Bp + 64);
    acc[ct] = __builtin_amdgcn_mfma_f32_16x16x32_bf16(a0, b0, acc[ct], 0, 0, 0);
    acc[ct] = __builtin_amdgcn_mfma_f32_16x16x32_bf16(a1, b1, acc[ct], 0, 0, 0);
    acc[ct] = __builtin_amdgcn_mfma_f32_16x16x32_bf16(a2, b2, acc[ct], 0, 0, 0);
  }
  const int fbase = fB + wv * 16 + kg * 4;
#pragma unroll
  for (int ct = 0; ct < 10; ++ct) {
    const int c = ct * 16 + fidx;
    if (c < NCH) {
#pragma unroll
      for (int r = 0; r < 4; ++r) {
        const int f = fbase + r;
        if (f < NFRAMES) {
          float e = acc[ct][r];
          float edb = 3.0102999566f * __log2f(fmaf(e, 2.5e9f, 1e-12f));
          float xv = fminf(fmaxf(edb, 0.0f), 110.0f);
          float u2 = xv * (87.0f / 110.0f);
          int i0 = (int)u2; if (i0 > 86) i0 = 86;
          float fr = u2 - (float)i0;
          ninst[((size_t)row * NFRAMES + f) * NCH + c] =
              fmaf(luts[i0 + 1] - luts[i0], fr, luts[i0]);
        }
      }
    }
  }
}

// ================= short-term AGC (32-deep pipelined, branch-free main loop) =================
__global__ __launch_bounds__(64) void agc1(const float* __restrict__ ninst,
                                           float* __restrict__ stl) {
  int idx = blockIdx.x * 64 + threadIdx.x;
  if (idx >= NROWS * NCH) return;
  int row = idx / NCH, c = idx - row * NCH;
  const float* src = ninst + (size_t)row * NFRAMES * NCH + c;
  float* dst = stl + (size_t)row * NFRAMES * NCH + c;
  float buf[32], cur[32];
#pragma unroll
  for (int i = 0; i < 32; ++i) buf[i] = src[(size_t)i * NCH];
  float s = 0.0f;
  // main: f = 0..575 ; prefetch f+32 (max 607) unconditional
  for (int fb = 0; fb < 576; fb += 32) {
#pragma unroll
    for (int i = 0; i < 32; ++i) cur[i] = buf[i];
#pragma unroll
    for (int i = 0; i < 32; ++i) buf[i] = src[(size_t)(fb + 32 + i) * NCH];
#pragma unroll
    for (int j = 0; j < 32; ++j) {
      float xv = cur[j];
      float a = (xv > s) ? 0.045f : 0.033f;
      s = a * xv + (1.0f - a) * s;
      dst[(size_t)(fb + j) * NCH] = s;
    }
  }
  // tail: 576..607 from buf, then 608..624 direct
#pragma unroll
  for (int j = 0; j < 32; ++j) {
    float xv = buf[j];
    float a = (xv > s) ? 0.045f : 0.033f;
    s = a * xv + (1.0f - a) * s;
    dst[(size_t)(576 + j) * NCH] = s;
  }
  for (int f = 608; f < 625; ++f) {
    float xv = src[(size_t)f * NCH];
    float a = (xv > s) ? 0.045f : 0.033f;
    s = a * xv + (1.0f - a) * s;
    dst[(size_t)f * NCH] = s;
  }
}

// ================= ERB smoothing + binaural inhibition + channel sum, 8 frames/block =================
__global__ __launch_bounds__(256) void combine(const float* __restrict__ stl,
                                               const float* __restrict__ gauss,
                                               float* __restrict__ outL,
                                               float* __restrict__ outR) {
  __shared__ float sl[8][168], sr[8][168], gsh[17];
  const int b = blockIdx.y, fb = blockIdx.x * 8;
  const int tid = threadIdx.x;
  if (tid < 17) gsh[tid] = gauss[tid];
  for (int u = tid; u < 8 * 168; u += 256) {
    int fi = u / 168, c = u - fi * 168;
    sl[fi][c] = 0.0f; sr[fi][c] = 0.0f;
  }
  __syncthreads();
  for (int u = tid; u < 8 * 300; u += 256) {
    int fi = u / 300, r = u - fi * 300;
    int f = fb + fi;
    if (f < NFRAMES) {
      int ch = (r < NCH) ? 0 : 1;
      int c = (r < NCH) ? r : r - NCH;
      float v = stl[((size_t)(b * 2 + ch) * NFRAMES + f) * NCH + c];
      if (ch == 0) sl[fi][8 + c] = v; else sr[fi][8 + c] = v;
    }
  }
  __syncthreads();
  const int wv = tid >> 6, lane = tid & 63;
#pragma unroll
  for (int fi2 = 0; fi2 < 2; ++fi2) {
    const int fi = wv * 2 + fi2;
    const int f = fb + fi;
    float pvl = 0.0f, pvr = 0.0f;
#pragma unroll
    for (int s = 0; s < 3; ++s) {
      int c = lane + 64 * s;
      if (c < NCH) {
        float smL = 0.0f, smR = 0.0f;
#pragma unroll
        for (int t = 0; t < 17; ++t) {
          smL = fmaf(gsh[t], sl[fi][c + t], smL);
          smR = fmaf(gsh[t], sr[fi][c + t], smR);
        }
        float tR = __expf(-1.5978f * smR);
        float tL = __expf(-1.5978f * smL);
        pvl += smL * (2.0f * tR / fmaf(tR, tR, 1.0f));
        pvr += smR * (2.0f * tL / fmaf(tL, tL, 1.0f));
      }
    }
#pragma unroll
    for (int off = 32; off > 0; off >>= 1) {
      pvl += __shfl_xor(pvl, off);
      pvr += __shfl_xor(pvr, off);
    }
    if (lane == 0 && f < NFRAMES) {
      outL[b * NFRAMES + f] = pvl * 0.25f;
      outR[b * NFRAMES + f] = pvr * 0.25f;
    }
  }
}

// ================= long-term AGC + outputs: LDS-staged, 3-phase =================
__global__ __launch_bounds__(256) void final_k(const float* __restrict__ sLst,
                                               const float* __restrict__ sRst,
                                               float* __restrict__ out) {
  __shared__ float Ls[NB][641];
  __shared__ float Rs[NB][641];
  __shared__ float Lv[NB][641];
  const int tid = threadIdx.x;
  for (int u = tid; u < NB * NFRAMES; u += 256) {
    int b = u / NFRAMES, f = u - b * NFRAMES;
    float a = sLst[u];
    float c = sRst[u];
    Ls[b][f] = a;
    Rs[b][f] = c;
    out[u] = a + c;
  }
  __syncthreads();
  if (tid < NB) {
    const int b = tid;
    float ll = 0.0f, lr = 0.0f, mx = -3.4e38f;
    for (int f = 0; f < NFRAMES; ++f) {
      float a = Ls[b][f];
      float c = Rs[b][f];
      float aa = (a > ll) ? 0.01f : 0.00133f;
      ll = aa * a + (1.0f - aa) * ll;
      float ab = (c > lr) ? 0.01f : 0.00133f;
      lr = ab * c + (1.0f - ab) * lr;
      float lv = ll + lr;
      Lv[b][f] = lv;
      mx = fmaxf(mx, lv);
    }
    out[2 * NB * NFRAMES + b] = mx;
  }
  __syncthreads();
  for (int u = tid; u < NB * NFRAMES; u += 256) {
    int b = u / NFRAMES, f = u - b * NFRAMES;
    out[NB * NFRAMES + u] = Lv[b][f];
  }
}

extern "C" void kernel_launch(void* const* d_in, const int* in_sizes, int n_in,
                              void* d_out, int out_size, void* d_ws, size_t ws_size,
                              hipStream_t stream) {
  const float* audio = (const float*)d_in[0];
  const float* ear   = (const float*)d_in[1];
  const float* lut   = (const float*)d_in[2];
  char* ws = (char*)d_ws;

  unsigned short* BfT    = (unsigned short*)(ws);            // 7,864,320 B (fp16 x 8 replicas)
  float2*         coeffO = (float2*)(ws + 7864320);          //   260,608 B
  float*          Wmat   = (float*)(ws + 8124928);           //    40,200 B
  float*          gauss  = (float*)(ws + 8165128);           //        68 B
  float*          yedge  = (float*)(ws + 8165376);           //   393,216 B
  float*          Ibuf   = (float*)(ws + 8558592);           // 5,360,000 B
  float*          ninst  = (float*)(ws + 13918592);          // 12,000,000 B
  float*          stl    = (float*)(ws + 25918592);          // 12,000,000 B
  float*          stlL   = (float*)(ws + 37918592);          //    40,000 B
  float*          stlR   = (float*)(ws + 37958592);          //    40,000 B
  unsigned short* Wb16   = (unsigned short*)(ws + 37998592); //    30,720 B

  hipLaunchKernelGGL(setup_k, dim3(966), dim3(256), 0, stream,
                     ear, audio, coeffO, Wmat, gauss, BfT, yedge, Wb16);
  hipLaunchKernelGGL(sparse2, dim3(672), dim3(512), 0, stream,
                     audio, BfT, coeffO, yedge, Ibuf);
  hipLaunchKernelGGL(espec, dim3(10, 32), dim3(256), 0, stream, Ibuf, Wb16, lut, ninst);
  hipLaunchKernelGGL(agc1, dim3(75), dim3(64), 0, stream, ninst, stl);
  hipLaunchKernelGGL(combine, dim3(79, 16), dim3(256), 0, stream, stl, gauss, stlL, stlR);
  hipLaunchKernelGGL(final_k, dim3(1), dim3(256), 0, stream, stlL, stlR, (float*)d_out);
}

// Round 20
// 182.824 us; speedup vs baseline: 1.0289x; 1.0289x over previous
//
#include <hip/hip_runtime.h>
#include <hip/hip_bf16.h>
#include <math.h>

#define T_LEN   320000
#define NB      16
#define NROWS   32          // 16 batch * 2 ch
#define NFRAMES 625
#define NCOMP   67
#define NCH     150
#define HOPSZ   512

typedef __attribute__((ext_vector_type(8))) _Float16 half8v;
typedef __attribute__((ext_vector_type(8))) short short8v;
typedef __attribute__((ext_vector_type(4))) float f32x4;

// per-window constants
__constant__ int cW_N[6]  = {2048,1024,512,256,128,64};
__constant__ int cW_K0[6] = {2,3,8,10,11,9};
__constant__ int cW_CB[7] = {0,4,17,29,40,46,67};
__constant__ int cW_CO[7] = {0,8192,21504,27648,30464,31232,32576};
// fused-coefficient geometry (per window)
__constant__ int dNEp[6]  = {3072,2048,1536,1280,1152,1152};
__constant__ int dNEr[6]  = {3072,2048,1536,1280,1152,1088};
__constant__ int dBTb[7]  = {0,147456,245760,319488,380928,436224,491520}; // [w][col=48][k=NEp] ushort
// init_fused chunk mapping
__constant__ int dCPB[6]  = {12,8,6,5,5,5};
__constant__ int dCKB[7]  = {0,48,152,224,279,309,414};
// edge task list
__constant__ int eW[8] = {0,0,0,1,2,3,4,5};
__constant__ int eF[8] = {0,1,624,0,0,0,0,0};

// ---- uniform gemm task table: 12 tasks over 8 waves (fp16, 1-term) ----
__constant__ int tBb[12]   = {147456,180224,0,380928,0,436224,245760,454656,270336,473088,319488,339968};
__constant__ int tNEp[12]  = {2048,2048,3072,1152,3072,1152,1536,1152,1536,1152,1280,1280};
__constant__ int tStb[12]  = {512,512,0,960,0,992,768,992,768,992,896,896};
__constant__ int tKs0[12]  = {0,0,0,0,48,0,0,0,0,0,0,0};
__constant__ int tKs1[12]  = {64,64,48,36,96,36,48,36,48,36,40,40};
__constant__ int tJadd[12] = {4,12,0,40,0,46,17,54,25,62,29,37};
__constant__ int tNbL[12]  = {13,5,4,6,4,21,12,13,4,5,11,3};
__constant__ int tMode[12] = {0,0,1,0,2,0,0,0,0,0,0,0};
__constant__ int wStart[8] = {0,1,2,4,6,8,10,11};
__constant__ int wCnt[8]   = {1,1,2,2,2,2,1,1};

__device__ __forceinline__ unsigned short f2bf(float v) {
  unsigned u = __float_as_uint(v);
  return (unsigned short)((u + 0x7FFFu + ((u >> 16) & 1u)) >> 16);
}

// ================= setup: tables + fused fp16 B + edge FIR + roex-bf16 =================
// blocks [0,167): init_tables ; [167,581): init_fused ; [581,965): edge_y ; 965: Wb16
__global__ __launch_bounds__(256) void setup_k(const float* __restrict__ h,
                                               const float* __restrict__ x,
                                               float2* __restrict__ coeff,
                                               float* __restrict__ gauss,
                                               unsigned short* __restrict__ Bf,
                                               float* __restrict__ ye,
                                               unsigned short* __restrict__ Wb16) {
  __shared__ __align__(16) float sm[3585];
  const int bid = blockIdx.x, tid = threadIdx.x;
  if (bid < 167) {
    int gid = bid * 256 + tid;
    if (gid < 32576) {
      int w = 0;
      while (gid >= cW_CO[w + 1]) ++w;
      int local = gid - cW_CO[w];
      int N = cW_N[w];
      int jloc = local / N;
      int n = local - jloc * N;
      int k = cW_K0[w] + jloc;
      float win = 0.5f - 0.5f * cospif(2.0f * (float)n / (float)(N - 1));
      int r = (int)(((long long)k * (long long)n) % (long long)N);
      float ang = 2.0f * (float)r / (float)N;
      float scale = sqrtf(2.0f) / (0.5f * (float)(N - 1));
      float wc = win * scale;
      coeff[gid] = make_float2(wc * cospif(ang), wc * sinpif(ang));
    } else if (gid == 32576) {
      float tmp[17]; float s = 0.0f;
      for (int k = 0; k < 17; ++k) {
        float g = ((float)k - 8.0f) * 0.25f;
        tmp[k] = expf(-g * g / (2.0f * 0.08f * 0.08f));
        s += tmp[k];
      }
      for (int k = 0; k < 17; ++k) gauss[k] = tmp[k] / s;
    }
  } else if (bid < 581) {
    float* cre_l = sm;          // 1280
    float* cim_l = sm + 1280;   // 1280
    float* hs    = sm + 2560;   // 1025
    const int b2 = bid - 167;
    int w = 0;
    while (b2 >= dCKB[w + 1]) ++w;
    const int local = b2 - dCKB[w];
    const int jloc = local / dCPB[w];
    const int chunk = local - jloc * dCPB[w];
    const int N = cW_N[w];
    const int k = cW_K0[w] + jloc;
    const int NEp = dNEp[w], NEr = dNEr[w];
    const int v0 = chunk * 256;
    const int nlo_blk = max(0, v0 - 1024);
    const int nhi_blk = min(N - 1, v0 + 255);
    const int cnt_n = nhi_blk - nlo_blk + 1;
    const float scale = sqrtf(2.0f) / (0.5f * (float)(N - 1));
    for (int i = tid; i < 1025; i += 256) hs[i] = h[i];
    for (int i = tid; i < cnt_n; i += 256) {
      int n = nlo_blk + i;
      float win = 0.5f - 0.5f * cospif(2.0f * (float)n / (float)(N - 1));
      int r = (int)(((long long)k * (long long)n) % (long long)N);
      float ang = 2.0f * (float)r / (float)N;
      float wc = win * scale;
      cre_l[i] = wc * cospif(ang);
      cim_l[i] = wc * sinpif(ang);
    }
    __syncthreads();
    const int v = v0 + tid;
    if (v >= NEp) return;
    float re = 0.0f, im = 0.0f;
    if (v < NEr) {
      const int n0 = max(nlo_blk, v - 1024);
      const int n1 = min(nhi_blk, v);
      float r0 = 0.f, r1 = 0.f, r2 = 0.f, r3 = 0.f;
      float m0 = 0.f, m1 = 0.f, m2 = 0.f, m3 = 0.f;
      int n = n0;
      const int hoff = 1024 - v, coff = -nlo_blk;
      for (; n + 3 <= n1; n += 4) {
        float h0 = hs[n + hoff],     h1 = hs[n + 1 + hoff];
        float h2 = hs[n + 2 + hoff], h3 = hs[n + 3 + hoff];
        r0 = fmaf(cre_l[n + coff],     h0, r0); m0 = fmaf(cim_l[n + coff],     h0, m0);
        r1 = fmaf(cre_l[n + 1 + coff], h1, r1); m1 = fmaf(cim_l[n + 1 + coff], h1, m1);
        r2 = fmaf(cre_l[n + 2 + coff], h2, r2); m2 = fmaf(cim_l[n + 2 + coff], h2, m2);
        r3 = fmaf(cre_l[n + 3 + coff], h3, r3); m3 = fmaf(cim_l[n + 3 + coff], h3, m3);
      }
      for (; n <= n1; ++n) {
        float hv = hs[n + hoff];
        r0 = fmaf(cre_l[n + coff], hv, r0);
        m0 = fmaf(cim_l[n + coff], hv, m0);
      }
      re = (r0 + r1) + (r2 + r3);
      im = (m0 + m1) + (m2 + m3);
    }
    size_t o0 = (size_t)dBTb[w] + (size_t)(2 * jloc) * NEp + v;
    size_t o1 = o0 + NEp;
    _Float16 hr = (_Float16)re;
    _Float16 hi2 = (_Float16)im;
    Bf[o0] = *(unsigned short*)&hr;
    Bf[o1] = *(unsigned short*)&hi2;
  } else if (bid < 965) {
    float* xl = sm;             // 1280  (16B aligned)
    float* hs = sm + 1280;      // 1025  (offset 5120B, 16B aligned)
    const int b2 = bid - 581;
    const int chunk = b2 % 12, row = b2 / 12;
    const size_t rowoff = (size_t)row * T_LEN;
    const int i0 = chunk * 256;
    const int pos0 = (i0 < 1536) ? i0 : 318464 + (i0 - 1536);
    for (int i = tid; i < 1025; i += 256) hs[i] = h[i];
    for (int i = tid; i < 1280; i += 256) {
      int g = pos0 - 512 + i;
      xl[i] = ((unsigned)g < (unsigned)T_LEN) ? x[rowoff + g] : 0.0f;
    }
    __syncthreads();
    float a0 = 0.0f, a1 = 0.0f, a2 = 0.0f, a3 = 0.0f;
    const int d = tid + 1024;
    const float4* hs4 = (const float4*)hs;
    for (int m = 0; m < 1024; m += 4) {
      float4 hv = hs4[m >> 2];          // broadcast ds_read_b128: 4 taps/instr
      a0 = fmaf(hv.x, xl[d - m],     a0);
      a1 = fmaf(hv.y, xl[d - m - 1], a1);
      a2 = fmaf(hv.z, xl[d - m - 2], a2);
      a3 = fmaf(hv.w, xl[d - m - 3], a3);
    }
    float acc = ((a0 + a1) + (a2 + a3)) + hs[1024] * xl[d - 1024];
    ye[(size_t)row * 3072 + i0 + tid] = acc;
  } else {
    // roex table as bf16, B-layout [col=160][k=96]
    for (int u = tid; u < 160 * 96; u += 256) {
      int c = u / 96, j = u - (u / 96) * 96;
      float val = 0.0f;
      if (c < NCH && j < NCOMP) {
        float erb = 1.75f + 0.25f * (float)c;
        float fc = (exp10f(erb * (1.0f / 21.366f)) - 1.0f) * (1.0f / 0.004368f);
        float erbw = 24.673f * (0.004368f * fc + 1.0f);
        float p = 4.0f * fc / erbw;
        int w = 0;
        while (j >= cW_CB[w + 1]) ++w;
        float freq = (float)(cW_K0[w] + (j - cW_CB[w])) * (32000.0f / (float)cW_N[w]);
        float g = fabsf(freq / fc - 1.0f);
        float pg = p * g;
        val = (1.0f + pg) * expf(-pg);
      }
      Wb16[u] = f2bf(val);
    }
  }
}

// ================= MFMA fused FIR+DFT: fp16 single-term, uniform task loop =================
#define TILE_X 18944   // 31*512 + 3072
#define SWZ4(i) ((i) ^ ((((i) >> 9) & 15) << 3))

// blocks [0,640): MFMA gemm (fblk = b%20, row = b/20) ; [640,672): edge DFT (row = b-640)
__global__ __launch_bounds__(512) void sparse2(const float* __restrict__ x,
                                               const unsigned short* __restrict__ Bf,
                                               const float2* __restrict__ coeff,
                                               const float* __restrict__ ye,
                                               float* __restrict__ Ibuf) {
  __shared__ __align__(16) unsigned short sxh[TILE_X];   // fp16 x-tile
  __shared__ float redA[512];                            // W0a partials (2 KB)
  const int b = blockIdx.x, tid = threadIdx.x;
  if (b < 640) {
    const int fblk = b % 20, row = b / 20;
    const int f0 = fblk * 32;
    const float* xr = x + (size_t)row * T_LEN;
    const int lo = f0 * HOPSZ - 1536;
    for (int i = 4 * tid; i < TILE_X; i += 2048) {
      const int g = lo + i;
      float v[4];
      if (g >= 0 && g + 4 <= T_LEN) {
        float4 p = *(const float4*)(xr + g);
        v[0] = p.x; v[1] = p.y; v[2] = p.z; v[3] = p.w;
      } else {
#pragma unroll
        for (int q = 0; q < 4; ++q) {
          int gg = g + q;
          v[q] = ((unsigned)gg < (unsigned)T_LEN) ? xr[gg] : 0.0f;
        }
      }
      unsigned short h4[4];
#pragma unroll
      for (int q = 0; q < 4; ++q) {
        _Float16 hv = (_Float16)v[q];
        h4[q] = *(unsigned short*)&hv;
      }
      const int is = SWZ4(i);
      *(ushort4*)(sxh + is) = make_ushort4(h4[0], h4[1], h4[2], h4[3]);
    }
    __syncthreads();
    const int wv = tid >> 6, lane = tid & 63;
    const int fidx = lane & 15, kg = lane >> 4;
    const int t0 = wStart[wv], tcnt = wCnt[wv];
    f32x4 pA = (f32x4){0.f,0.f,0.f,0.f};   // W0b partial (mode 2)
    f32x4 pB = (f32x4){0.f,0.f,0.f,0.f};
    for (int ti = t0; ti < t0 + tcnt; ++ti) {
      const int NEp = tNEp[ti];
      const int ks0 = tKs0[ti], ks1 = tKs1[ti];
      const unsigned short* Bp = Bf + tBb[ti] + fidx * NEp + kg * 8;
      const int ibase = fidx * 512 + tStb[ti] + kg * 8;
      f32x4 acc0 = (f32x4){0.f,0.f,0.f,0.f};
      f32x4 acc1 = (f32x4){0.f,0.f,0.f,0.f};
#pragma unroll 2
      for (int kk = ks0; kk < ks1; ++kk) {
        const int ko = kk * 32;
        half8v bv = *(const half8v*)(Bp + ko);
        half8v a0 = *(const half8v*)(sxh + SWZ4(ibase + ko));
        half8v a1 = *(const half8v*)(sxh + SWZ4(ibase + 8192 + ko));
        acc0 = __builtin_amdgcn_mfma_f32_16x16x32_f16(a0, bv, acc0, 0, 0, 0);
        acc1 = __builtin_amdgcn_mfma_f32_16x16x32_f16(a1, bv, acc1, 0, 0, 0);
      }
      const int mode = tMode[ti];
      if (mode == 0) {
        const int jadd = tJadd[ti], nbl = tNbL[ti];
        const int fh = fidx >> 1;
        const bool jvalid = !(fidx & 1) && fh < nbl;
#pragma unroll
        for (int r = 0; r < 4; ++r) {
          float v0 = acc0[r];
          float sq0 = v0 * v0;
          sq0 += __shfl_xor(sq0, 1);
          int fA = f0 + kg * 4 + r;
          if (jvalid && fA != 0)
            Ibuf[((size_t)row * NFRAMES + fA) * NCOMP + jadd + fh] = sq0;
          float v1 = acc1[r];
          float sq1 = v1 * v1;
          sq1 += __shfl_xor(sq1, 1);
          int fB = f0 + 16 + kg * 4 + r;
          if (jvalid && fB < NFRAMES)
            Ibuf[((size_t)row * NFRAMES + fB) * NCOMP + jadd + fh] = sq1;
        }
      } else if (mode == 1) {
#pragma unroll
        for (int r = 0; r < 4; ++r) {
          redA[lane * 4 + r] = acc0[r];
          redA[256 + lane * 4 + r] = acc1[r];
        }
      } else {
        pA = acc0; pB = acc1;
      }
    }
    __syncthreads();
    if (wv == 3) {
      // finalize W0: sum K-halves, square, pair re/im, store (jb0=0, nb=4)
#pragma unroll
      for (int r = 0; r < 4; ++r) {
        float v0 = pA[r] + redA[lane * 4 + r];
        float sq0 = v0 * v0;
        sq0 += __shfl_xor(sq0, 1);
        int fA = f0 + kg * 4 + r;
        float v1 = pB[r] + redA[256 + lane * 4 + r];
        float sq1 = v1 * v1;
        sq1 += __shfl_xor(sq1, 1);
        int fB = f0 + 16 + kg * 4 + r;
        if (!(fidx & 1)) {
          int j = fidx >> 1;
          if (j < 4) {
            bool eA = (fA == 0) || (fA == 1) || (fA == 624);
            if (!eA) Ibuf[((size_t)row * NFRAMES + fA) * NCOMP + j] = sq0;
            bool eB = (fB == 1) || (fB == 624);
            if (fB < NFRAMES && !eB) Ibuf[((size_t)row * NFRAMES + fB) * NCOMP + j] = sq1;
          }
        }
      }
    }
  } else {
    const int row = b - 640;
    float* yl = (float*)sxh;   // 12 KB alias
    for (int i = tid; i < 3072; i += 512) yl[i] = ye[(size_t)row * 3072 + i];
    __syncthreads();
    const int wv = tid >> 6, lane = tid & 63;
    const int w = eW[wv], f = eF[wv];
    const int N = cW_N[w];
    const int nb = cW_CB[w + 1] - cW_CB[w];
    for (int jl = 0; jl < nb; ++jl) {
      const float2* cf = coeff + cW_CO[w] + (size_t)jl * N;
      float re = 0.0f, im = 0.0f;
      for (int n = lane; n < N; n += 64) {
        int pos = f * HOPSZ - (N >> 1) + n;
        if ((unsigned)pos < (unsigned)T_LEN) {
          int yi = (pos < 1536) ? pos : (pos - 318464 + 1536);
          float yv = yl[yi];
          float2 cs = cf[n];
          re = fmaf(yv, cs.x, re);
          im = fmaf(yv, cs.y, im);
        }
      }
#pragma unroll
      for (int off = 32; off > 0; off >>= 1) {
        re += __shfl_xor(re, off);
        im += __shfl_xor(im, off);
      }
      if (lane == 0)
        Ibuf[((size_t)row * NFRAMES + f) * NCOMP + (cW_CB[w] + jl)] = re * re + im * im;
    }
  }
}

// ================= E = I@W via bf16 MFMA -> dB -> LUT -> n_inst, 64 frames/block =================
__global__ __launch_bounds__(256) void espec(const float* __restrict__ Ibuf,
                                             const unsigned short* __restrict__ Wb16,
                                             const float* __restrict__ lut,
                                             float* __restrict__ ninst) {
  __shared__ __align__(16) unsigned short sxA[64 * 104];   // bf16 I, stride 104
  __shared__ float luts[88];
  const int row = blockIdx.y;
  const int fB = blockIdx.x * 64;
  const int tid = threadIdx.x;
  if (tid < 88) luts[tid] = lut[tid];
  for (int u = tid; u < 64 * 52; u += 256) ((unsigned*)sxA)[u] = 0;
  __syncthreads();
  for (int u = tid; u < 64 * NCOMP; u += 256) {
    int fl = u / NCOMP, j = u - fl * NCOMP;
    int f = fB + fl;
    float v = (f < NFRAMES) ? Ibuf[((size_t)row * NFRAMES + f) * NCOMP + j] : 0.0f;
    sxA[fl * 104 + j] = f2bf(v);
  }
  __syncthreads();
  const int wv = tid >> 6, lane = tid & 63;
  const int fidx = lane & 15, kg = lane >> 4;
  const unsigned short* Ap = sxA + (wv * 16 + fidx) * 104 + kg * 8;
  short8v a0 = *(const short8v*)(Ap);
  short8v a1 = *(const short8v*)(Ap + 32);
  short8v a2 = *(const short8v*)(Ap + 64);
  f32x4 acc[10];
#pragma unroll
  for (int ct = 0; ct < 10; ++ct) acc[ct] = (f32x4){0.f,0.f,0.f,0.f};
#pragma unroll
  for (int ct = 0; ct < 10; ++ct) {
    const unsigned short* Bp = Wb16 + (ct * 16 + fidx) * 96 + kg * 8;
    short8v b0 = *(const short8v*)(Bp);
    short8v b1 = *(const short8v*)(Bp + 32);
    short8v b2 = *(const short8v*)(Bp + 64);
    acc[ct] = __builtin_amdgcn_mfma_f32_16x16x32_bf16(a0, b0, acc[ct], 0, 0, 0);
    acc[ct] = __builtin_amdgcn_mfma_f32_16x16x32_bf16(a1, b1, acc[ct], 0, 0, 0);
    acc[ct] = __builtin_amdgcn_mfma_f32_16x16x32_bf16(a2, b2, acc[ct], 0, 0, 0);
  }
  const int fbase = fB + wv * 16 + kg * 4;
#pragma unroll
  for (int ct = 0; ct < 10; ++ct) {
    const int c = ct * 16 + fidx;
    if (c < NCH) {
#pragma unroll
      for (int r = 0; r < 4; ++r) {
        const int f = fbase + r;
        if (f < NFRAMES) {
          float e = acc[ct][r];
          float edb = 3.0102999566f * __log2f(fmaf(e, 2.5e9f, 1e-12f));
          float xv = fminf(fmaxf(edb, 0.0f), 110.0f);
          float u2 = xv * (87.0f / 110.0f);
          int i0 = (int)u2; if (i0 > 86) i0 = 86;
          float fr = u2 - (float)i0;
          ninst[((size_t)row * NFRAMES + f) * NCH + c] =
              fmaf(luts[i0 + 1] - luts[i0], fr, luts[i0]);
        }
      }
    }
  }
}

// ================= short-term AGC (32-deep pipelined, branch-free main loop) =================
__global__ __launch_bounds__(64) void agc1(const float* __restrict__ ninst,
                                           float* __restrict__ stl) {
  int idx = blockIdx.x * 64 + threadIdx.x;
  if (idx >= NROWS * NCH) return;
  int row = idx / NCH, c = idx - row * NCH;
  const float* src = ninst + (size_t)row * NFRAMES * NCH + c;
  float* dst = stl + (size_t)row * NFRAMES * NCH + c;
  float buf[32], cur[32];
#pragma unroll
  for (int i = 0; i < 32; ++i) buf[i] = src[(size_t)i * NCH];
  float s = 0.0f;
  for (int fb = 0; fb < 576; fb += 32) {
#pragma unroll
    for (int i = 0; i < 32; ++i) cur[i] = buf[i];
#pragma unroll
    for (int i = 0; i < 32; ++i) buf[i] = src[(size_t)(fb + 32 + i) * NCH];
#pragma unroll
    for (int j = 0; j < 32; ++j) {
      float xv = cur[j];
      float a = (xv > s) ? 0.045f : 0.033f;
      s = a * xv + (1.0f - a) * s;
      dst[(size_t)(fb + j) * NCH] = s;
    }
  }
#pragma unroll
  for (int j = 0; j < 32; ++j) {
    float xv = buf[j];
    float a = (xv > s) ? 0.045f : 0.033f;
    s = a * xv + (1.0f - a) * s;
    dst[(size_t)(576 + j) * NCH] = s;
  }
  for (int f = 608; f < 625; ++f) {
    float xv = src[(size_t)f * NCH];
    float a = (xv > s) ? 0.045f : 0.033f;
    s = a * xv + (1.0f - a) * s;
    dst[(size_t)f * NCH] = s;
  }
}

// ================= ERB smoothing + binaural inhibition + channel sum, 8 frames/block =================
__global__ __launch_bounds__(256) void combine(const float* __restrict__ stl,
                                               const float* __restrict__ gauss,
                                               float* __restrict__ outL,
                                               float* __restrict__ outR) {
  __shared__ float sl[8][168], sr[8][168], gsh[17];
  const int b = blockIdx.y, fb = blockIdx.x * 8;
  const int tid = threadIdx.x;
  if (tid < 17) gsh[tid] = gauss[tid];
  for (int u = tid; u < 8 * 168; u += 256) {
    int fi = u / 168, c = u - fi * 168;
    sl[fi][c] = 0.0f; sr[fi][c] = 0.0f;
  }
  __syncthreads();
  for (int u = tid; u < 8 * 300; u += 256) {
    int fi = u / 300, r = u - fi * 300;
    int f = fb + fi;
    if (f < NFRAMES) {
      int ch = (r < NCH) ? 0 : 1;
      int c = (r < NCH) ? r : r - NCH;
      float v = stl[((size_t)(b * 2 + ch) * NFRAMES + f) * NCH + c];
      if (ch == 0) sl[fi][8 + c] = v; else sr[fi][8 + c] = v;
    }
  }
  __syncthreads();
  const int wv = tid >> 6, lane = tid & 63;
#pragma unroll
  for (int fi2 = 0; fi2 < 2; ++fi2) {
    const int fi = wv * 2 + fi2;
    const int f = fb + fi;
    float pvl = 0.0f, pvr = 0.0f;
#pragma unroll
    for (int s = 0; s < 3; ++s) {
      int c = lane + 64 * s;
      if (c < NCH) {
        float smL = 0.0f, smR = 0.0f;
#pragma unroll
        for (int t = 0; t < 17; ++t) {
          smL = fmaf(gsh[t], sl[fi][c + t], smL);
          smR = fmaf(gsh[t], sr[fi][c + t], smR);
        }
        float tR = __expf(-1.5978f * smR);
        float tL = __expf(-1.5978f * smL);
        pvl += smL * (2.0f * tR / fmaf(tR, tR, 1.0f));
        pvr += smR * (2.0f * tL / fmaf(tL, tL, 1.0f));
      }
    }
#pragma unroll
    for (int off = 32; off > 0; off >>= 1) {
      pvl += __shfl_xor(pvl, off);
      pvr += __shfl_xor(pvr, off);
    }
    if (lane == 0 && f < NFRAMES) {
      outL[b * NFRAMES + f] = pvl * 0.25f;
      outR[b * NFRAMES + f] = pvr * 0.25f;
    }
  }
}

// ================= long-term AGC + outputs: LDS-staged, 3-phase =================
__global__ __launch_bounds__(256) void final_k(const float* __restrict__ sLst,
                                               const float* __restrict__ sRst,
                                               float* __restrict__ out) {
  __shared__ float Ls[NB][641];
  __shared__ float Rs[NB][641];
  __shared__ float Lv[NB][641];
  const int tid = threadIdx.x;
  for (int u = tid; u < NB * NFRAMES; u += 256) {
    int b = u / NFRAMES, f = u - b * NFRAMES;
    float a = sLst[u];
    float c = sRst[u];
    Ls[b][f] = a;
    Rs[b][f] = c;
    out[u] = a + c;
  }
  __syncthreads();
  if (tid < NB) {
    const int b = tid;
    float ll = 0.0f, lr = 0.0f, mx = -3.4e38f;
    for (int f = 0; f < NFRAMES; ++f) {
      float a = Ls[b][f];
      float c = Rs[b][f];
      float aa = (a > ll) ? 0.01f : 0.00133f;
      ll = aa * a + (1.0f - aa) * ll;
      float ab = (c > lr) ? 0.01f : 0.00133f;
      lr = ab * c + (1.0f - ab) * lr;
      float lv = ll + lr;
      Lv[b][f] = lv;
      mx = fmaxf(mx, lv);
    }
    out[2 * NB * NFRAMES + b] = mx;
  }
  __syncthreads();
  for (int u = tid; u < NB * NFRAMES; u += 256) {
    int b = u / NFRAMES, f = u - b * NFRAMES;
    out[NB * NFRAMES + u] = Lv[b][f];
  }
}

extern "C" void kernel_launch(void* const* d_in, const int* in_sizes, int n_in,
                              void* d_out, int out_size, void* d_ws, size_t ws_size,
                              hipStream_t stream) {
  const float* audio = (const float*)d_in[0];
  const float* ear   = (const float*)d_in[1];
  const float* lut   = (const float*)d_in[2];
  char* ws = (char*)d_ws;

  unsigned short* BfT    = (unsigned short*)(ws);            //   983,040 B (fp16, single copy)
  float2*         coeffO = (float2*)(ws + 983040);           //   260,608 B
  float*          gauss  = (float*)(ws + 1243648);           //        68 B
  float*          yedge  = (float*)(ws + 1243904);           //   393,216 B
  float*          Ibuf   = (float*)(ws + 1637120);           // 5,360,000 B
  float*          ninst  = (float*)(ws + 6997120);           // 12,000,000 B
  float*          stl    = (float*)(ws + 18997120);          // 12,000,000 B
  float*          stlL   = (float*)(ws + 30997120);          //    40,000 B
  float*          stlR   = (float*)(ws + 31037120);          //    40,000 B
  unsigned short* Wb16   = (unsigned short*)(ws + 31077120); //    30,720 B

  hipLaunchKernelGGL(setup_k, dim3(966), dim3(256), 0, stream,
                     ear, audio, coeffO, gauss, BfT, yedge, Wb16);
  hipLaunchKernelGGL(sparse2, dim3(672), dim3(512), 0, stream,
                     audio, BfT, coeffO, yedge, Ibuf);
  hipLaunchKernelGGL(espec, dim3(10, 32), dim3(256), 0, stream, Ibuf, Wb16, lut, ninst);
  hipLaunchKernelGGL(agc1, dim3(75), dim3(64), 0, stream, ninst, stl);
  hipLaunchKernelGGL(combine, dim3(79, 16), dim3(256), 0, stream, stl, gauss, stlL, stlR);
  hipLaunchKernelGGL(final_k, dim3(1), dim3(256), 0, stream, stlL, stlR, (float*)d_out);
}